// Round 6
// baseline (324.595 us; speedup 1.0000x reference)
//
#include <hip/hip_runtime.h>
#include <hip/hip_bf16.h>
#include <math.h>

// BinaryTreeLSTM — round 6: batched x-GEMM (GX = emb@W_ih.T + b for ALL nodes,
// one M=4096 dispatch), per-level GEMMs reduced to K=2048 (W_hh only),
// compact c storage (only even-node c is read), bias folded into GX.
//
// Layouts:
//  Wih_p[4096][1024], Whh_p[4096][2048]: effective rows e=g*1024+j (W row
//    g*2048+j), XCD-affine row order (row-tile e/128 written by block b with
//    b&7 == (e/128)%8, matching the GEMM unswizzle).
//  GX[4096][4096] fp32: GX[r] = bf16(emb[r]) @ Wih_p.T + bg  (r = node id).
//  Hcat: level-k A-slab at row OFF(k)=4096-2^(k+1), 2^k rows x 2048 bf16;
//    act of level k+1 writes h of node m to row m>>1, col (m&1)*1024.
//  c compact: act of level k writes c of even nodes only: row m>>1 (fp32,
//    1024 wide); act of level k-1 reads row m (= node 2m's c).

#define HDIM 1024
#define TREE_DEPTH 12
#define GCOLS 4096

typedef unsigned short u16;
typedef unsigned int u32;
typedef __attribute__((ext_vector_type(8))) short bf16x8;
typedef __attribute__((ext_vector_type(4))) float f32x4;

__device__ __forceinline__ void gload16(const void* g, void* l) {
    __builtin_amdgcn_global_load_lds(
        (const __attribute__((address_space(1))) u32*)g,
        (__attribute__((address_space(3))) u32*)l, 16, 0, 0);
}

__device__ __forceinline__ u16 f2bf(float f) {
    __hip_bfloat16 h = __float2bfloat16(f);
    return *reinterpret_cast<u16*>(&h);
}

// ---------------------------------------------------------------- converts
__global__ void bias_kernel(const float* __restrict__ b_ih,
                            const float* __restrict__ b_hh,
                            float* __restrict__ bg) {
    int idx = blockIdx.x * blockDim.x + threadIdx.x;   // 0..4095
    int g = idx >> 10, j = idx & 1023;
    int r = g * 2048 + j;
    bg[idx] = b_ih[r] + b_hh[r];
}

// Pack W_ih -> Wih_p[4096][1024], W_hh -> Whh_p[4096][2048], XCD-affine.
__global__ void pack_w(const float* __restrict__ Wih,
                       const float* __restrict__ Whh,
                       u16* __restrict__ Wih_p, u16* __restrict__ Whh_p) {
    const int b = blockIdx.x;          // 0..4095
    const int seg = blockIdx.y;        // 0: ih, 1/2: hh halves
    const int x = b & 7, t = b >> 3;   // t in [0,512)
    const int e = x * 128 + (t & 127) + (t >> 7) * 1024;   // (e/128)%8 == x
    const int wr = (e >> 10) * 2048 + (e & 1023);
    const int col = threadIdx.x * 4;   // 0..1020
    float4 v;
    u16* dst;
    if (seg == 0) {
        v = *reinterpret_cast<const float4*>(Wih + (size_t)wr * 1024 + col);
        dst = Wih_p + (size_t)e * 1024 + col;
    } else {
        v = *reinterpret_cast<const float4*>(Whh + (size_t)wr * 2048 + (seg - 1) * 1024 + col);
        dst = Whh_p + (size_t)e * 2048 + (seg - 1) * 1024 + col;
    }
    uint2 p = make_uint2((u32)f2bf(v.x) | ((u32)f2bf(v.y) << 16),
                         (u32)f2bf(v.z) | ((u32)f2bf(v.w) << 16));
    *reinterpret_cast<uint2*>(dst) = p;
}

__global__ void conv_emb(const float* __restrict__ emb, u16* __restrict__ xb) {
    size_t idx = ((size_t)blockIdx.x * 256 + threadIdx.x) * 4;  // over 4095*1024
    float4 v = *reinterpret_cast<const float4*>(emb + idx);
    uint2 p = make_uint2((u32)f2bf(v.x) | ((u32)f2bf(v.y) << 16),
                         (u32)f2bf(v.z) | ((u32)f2bf(v.w) << 16));
    *reinterpret_cast<uint2*>(xb + idx) = p;
}

// ------------------------------------------------------- block-id unswizzle
// Weight slab s = sl*8 + (b&7): all blocks of slab s land on XCD s%8
// (ct%8 == b&7 since 8|gy) at every level -> stable weight<->XCD affinity.
__device__ __forceinline__ void unswizzle(int gx, int gy, int& mt, int& ct, int& ks) {
    int b = blockIdx.x + gx * (blockIdx.y + gy * blockIdx.z);
    const int x = b & 7, t = b >> 3;
    mt = t % gx;
    const int sl = t / gx;
    const int s = sl * 8 + x;
    ct = s % gy;
    ks = s / gy;
}

// ---------------------------------------------------------------- big GEMM
// M multiple of 128. Tile 128x128, BK=32, 4 waves (64x64 each).
__global__ __launch_bounds__(256) void gemm_big(
    const u16* __restrict__ A, int lda,
    const u16* __restrict__ W, int ldw,
    const float* __restrict__ bias,   // null for h-gemms
    float* __restrict__ partials,     // KS slabs of n*4096
    int n, int kchunk)
{
    __shared__ u16 As[128][32];
    __shared__ u16 Bs[128][32];

    int mt, ct, ks;
    unswizzle(gridDim.x, gridDim.y, mt, ct, ks);

    const int m0 = mt * 128;
    const int c0 = ct * 128;
    const int kbeg = ks * kchunk;
    float* gout = partials + (size_t)ks * n * GCOLS;

    const int tid  = threadIdx.x;
    const int lane = tid & 63;
    const int w    = tid >> 6;
    const int wr   = (w >> 1) * 64;
    const int wc   = (w & 1) * 64;

    f32x4 acc[4][4];
    #pragma unroll
    for (int i = 0; i < 4; ++i)
        #pragma unroll
        for (int j = 0; j < 4; ++j)
            acc[i][j] = f32x4{0.f, 0.f, 0.f, 0.f};

    const int crow = lane >> 2;        // 0..15
    const int ck   = (lane & 3) * 8;   // 0,8,16,24

    const u16* pA0 = A + (size_t)(m0 + (w * 2 + 0) * 16 + crow) * lda + kbeg + ck;
    const u16* pA1 = A + (size_t)(m0 + (w * 2 + 1) * 16 + crow) * lda + kbeg + ck;
    const u16* pB0 = W + (size_t)(c0 + (w * 2 + 0) * 16 + crow) * ldw + kbeg + ck;
    const u16* pB1 = W + (size_t)(c0 + (w * 2 + 1) * 16 + crow) * ldw + kbeg + ck;

    const int fl = lane & 15;
    const int kb = (lane >> 4) * 8;

    for (int k0 = 0; k0 < kchunk; k0 += 32) {
        gload16(pA0, &As[(w * 2 + 0) * 16][0]);
        gload16(pA1, &As[(w * 2 + 1) * 16][0]);
        gload16(pB0, &Bs[(w * 2 + 0) * 16][0]);
        gload16(pB1, &Bs[(w * 2 + 1) * 16][0]);
        pA0 += 32; pA1 += 32; pB0 += 32; pB1 += 32;
        __syncthreads();

        bf16x8 a[4], b[4];
        #pragma unroll
        for (int i = 0; i < 4; ++i)
            a[i] = *reinterpret_cast<const bf16x8*>(&As[wr + i * 16 + fl][kb]);
        #pragma unroll
        for (int j = 0; j < 4; ++j)
            b[j] = *reinterpret_cast<const bf16x8*>(&Bs[wc + j * 16 + fl][kb]);
        #pragma unroll
        for (int i = 0; i < 4; ++i)
            #pragma unroll
            for (int j = 0; j < 4; ++j)
                acc[i][j] = __builtin_amdgcn_mfma_f32_16x16x32_bf16(a[i], b[j], acc[i][j], 0, 0, 0);
        __syncthreads();
    }

    const int rg = (lane >> 4) * 4;
    #pragma unroll
    for (int i = 0; i < 4; ++i)
        #pragma unroll
        for (int j = 0; j < 4; ++j) {
            const int c = c0 + wc + j * 16 + fl;
            const float bv = bias ? bias[c] : 0.f;
            #pragma unroll
            for (int r = 0; r < 4; ++r) {
                const int m = m0 + wr + i * 16 + rg + r;
                gout[(size_t)m * GCOLS + c] = acc[i][j][r] + bv;
            }
        }
}

// ---------------------------------------------------------------- small GEMM
// n <= 64. BM=16, BN=128, K=2048 split 16 ways (kchunk=128).
__global__ __launch_bounds__(256) void gemm_small(
    const u16* __restrict__ A,       // level slab: n x 2048
    const u16* __restrict__ W,       // Whh_p: 4096 x 2048
    float* __restrict__ partials,    // 16 slabs of n*4096
    int n, int kchunk)
{
    __shared__ u16 As[16][32];
    __shared__ u16 Bs[128][32];

    int mt, ct, ks;
    unswizzle(gridDim.x, gridDim.y, mt, ct, ks);

    const int m0 = mt * 16;
    const int c0 = ct * 128;
    const int kbeg = ks * kchunk;

    const int tid  = threadIdx.x;
    const int lane = tid & 63;
    const int w    = tid >> 6;

    f32x4 acc0 = f32x4{0.f, 0.f, 0.f, 0.f};
    f32x4 acc1 = f32x4{0.f, 0.f, 0.f, 0.f};

    const int arow = tid >> 4;            // 0..15
    const int ak   = (tid & 15) * 2;      // 0..30 even
    const int crow = lane >> 2;
    const int ck   = (lane & 3) * 8;

    const int mA = m0 + arow;
    const u16* pA  = A + (size_t)mA * 2048 + kbeg + ak;     // guarded
    const u16* pB0 = W + (size_t)(c0 + w * 32 + 0  + crow) * 2048 + kbeg + ck;
    const u16* pB1 = W + (size_t)(c0 + w * 32 + 16 + crow) * 2048 + kbeg + ck;

    const int fl = lane & 15;
    const int kb = (lane >> 4) * 8;

    for (int k0 = 0; k0 < kchunk; k0 += 32) {
        u32 av = 0;
        if (mA < n) av = *reinterpret_cast<const u32*>(pA);
        pA += 32;
        gload16(pB0, &Bs[w * 32 + 0][0]);
        gload16(pB1, &Bs[w * 32 + 16][0]);
        pB0 += 32; pB1 += 32;
        *reinterpret_cast<u32*>(&As[arow][ak]) = av;
        __syncthreads();

        bf16x8 a  = *reinterpret_cast<const bf16x8*>(&As[fl][kb]);
        bf16x8 b0 = *reinterpret_cast<const bf16x8*>(&Bs[w * 32 + 0  + fl][kb]);
        bf16x8 b1 = *reinterpret_cast<const bf16x8*>(&Bs[w * 32 + 16 + fl][kb]);
        acc0 = __builtin_amdgcn_mfma_f32_16x16x32_bf16(a, b0, acc0, 0, 0, 0);
        acc1 = __builtin_amdgcn_mfma_f32_16x16x32_bf16(a, b1, acc1, 0, 0, 0);
        __syncthreads();
    }

    const int rg = (lane >> 4) * 4;
    float* gout = partials + (size_t)ks * n * GCOLS;
    #pragma unroll
    for (int r = 0; r < 4; ++r) {
        const int m = m0 + rg + r;
        if (m < n) {
            gout[(size_t)m * GCOLS + c0 + w * 32 + 0  + fl] = acc0[r];
            gout[(size_t)m * GCOLS + c0 + w * 32 + 16 + fl] = acc1[r];
        }
    }
}

// ---------------------------------------------------------------- LSTM cell
// gates = gx (bias included) + sum of ks_n partial slabs.
__global__ void level_act(const float* __restrict__ parts, int ks_n, size_t ks_stride,
                          const float* __restrict__ gx,      // n x 4096 fp32
                          const float* __restrict__ cprev,   // compact c, 1024-wide
                          u16* __restrict__ hnext,           // next slab base (or null)
                          float* __restrict__ cnext,         // compact c out
                          float* __restrict__ out,           // null unless n==1
                          int n, int has_h)
{
    int idx = blockIdx.x * blockDim.x + threadIdx.x;   // over n*256
    if (idx >= n * 256) return;
    int m = idx >> 8, j4 = (idx & 255) * 4;

    const float* g = gx + (size_t)m * GCOLS;
    float4 iv = *reinterpret_cast<const float4*>(g + j4);
    float4 fv = *reinterpret_cast<const float4*>(g + 1024 + j4);
    float4 gv = *reinterpret_cast<const float4*>(g + 2048 + j4);
    float4 ov = *reinterpret_cast<const float4*>(g + 3072 + j4);
    for (int s = 0; s < ks_n; ++s) {
        const float* p = parts + (size_t)s * ks_stride + (size_t)m * GCOLS;
        float4 a = *reinterpret_cast<const float4*>(p + j4);
        float4 b = *reinterpret_cast<const float4*>(p + 1024 + j4);
        float4 c = *reinterpret_cast<const float4*>(p + 2048 + j4);
        float4 d = *reinterpret_cast<const float4*>(p + 3072 + j4);
        iv.x += a.x; iv.y += a.y; iv.z += a.z; iv.w += a.w;
        fv.x += b.x; fv.y += b.y; fv.z += b.z; fv.w += b.w;
        gv.x += c.x; gv.y += c.y; gv.z += c.z; gv.w += c.w;
        ov.x += d.x; ov.y += d.y; ov.z += d.z; ov.w += d.w;
    }
    float4 cc = make_float4(0.f, 0.f, 0.f, 0.f);
    if (has_h) cc = *reinterpret_cast<const float4*>(cprev + (size_t)m * 1024 + j4);

    float cn[4], hn[4];
    float ivv[4] = {iv.x, iv.y, iv.z, iv.w};
    float fvv[4] = {fv.x, fv.y, fv.z, fv.w};
    float gvv[4] = {gv.x, gv.y, gv.z, gv.w};
    float ovv[4] = {ov.x, ov.y, ov.z, ov.w};
    float ccv[4] = {cc.x, cc.y, cc.z, cc.w};
    #pragma unroll
    for (int t = 0; t < 4; ++t) {
        float si = 1.0f / (1.0f + expf(-ivv[t]));
        float sf = 1.0f / (1.0f + expf(-fvv[t]));
        float so = 1.0f / (1.0f + expf(-ovv[t]));
        cn[t] = sf * ccv[t] + si * tanhf(gvv[t]);
        hn[t] = so * tanhf(cn[t]);
    }
    if (hnext) {
        uint2 hp = make_uint2((u32)f2bf(hn[0]) | ((u32)f2bf(hn[1]) << 16),
                              (u32)f2bf(hn[2]) | ((u32)f2bf(hn[3]) << 16));
        *reinterpret_cast<uint2*>(hnext + (size_t)(m >> 1) * 2048 +
                                  (m & 1) * 1024 + j4) = hp;
    }
    if (!(m & 1))
        *reinterpret_cast<float4*>(cnext + (size_t)(m >> 1) * 1024 + j4) =
            make_float4(cn[0], cn[1], cn[2], cn[3]);
    if (out) {
        *reinterpret_cast<float4*>(out + j4) = make_float4(hn[0], hn[1], hn[2], hn[3]);
        *reinterpret_cast<float4*>(out + 1024 + j4) = make_float4(cn[0], cn[1], cn[2], cn[3]);
    }
}

// ---------------------------------------------------------------- launcher
extern "C" void kernel_launch(void* const* d_in, const int* in_sizes, int n_in,
                              void* d_out, int out_size, void* d_ws, size_t ws_size,
                              hipStream_t stream) {
    const float* emb  = (const float*)d_in[0];
    const float* W_ih = (const float*)d_in[1];
    const float* W_hh = (const float*)d_in[2];
    const float* b_ih = (const float*)d_in[3];
    const float* b_hh = (const float*)d_in[4];
    float* out = (float*)d_out;

    char* p = (char*)d_ws;
    float* bg    = (float*)p;   p += 16384;
    u16* Wih_p   = (u16*)p;     p += (size_t)4096 * 1024 * 2;       //  8.4 MB
    u16* Whh_p   = (u16*)p;     p += (size_t)4096 * 2048 * 2;       // 16.8 MB
    u16* xb      = (u16*)p;     p += (size_t)4096 * 1024 * 2;       //  8.4 MB
    float* GX    = (float*)p;   p += (size_t)4096 * 4096 * 4;       // 67.1 MB
    float* parts = (float*)p;   p += (size_t)2048 * 4096 * 4;       // 33.6 MB
    u16* Hcat    = (u16*)p;     p += (size_t)(4096 + 64) * 2048 * 2;// 17.0 MB
    float* cbA   = (float*)p;   p += (size_t)1024 * 1024 * 4;       //  4.2 MB
    float* cbB   = (float*)p;   p += (size_t)1024 * 1024 * 4;       //  4.2 MB

    bias_kernel<<<16, 256, 0, stream>>>(b_ih, b_hh, bg);
    {
        dim3 g(4096, 3);
        pack_w<<<g, 256, 0, stream>>>(W_ih, W_hh, Wih_p, Whh_p);
    }
    conv_emb<<<4095, 256, 0, stream>>>(emb, xb);

    // GX = xb @ Wih_p.T + bg for all 4096 (4095 used) nodes.
    gemm_big<<<dim3(32, 32, 1), 256, 0, stream>>>(
        xb, 1024, Wih_p, 1024, bg, GX, 4096, 1024);

    // OFF(k) = 4096 - 2^(k+1): level-k slab base row in Hcat.
    #define OFF(k) (4096 - (2 << (k)))

    // level 11: gates = GX rows only.
    level_act<<<2048, 256, 0, stream>>>(
        nullptr, 0, 0, GX + (size_t)2047 * GCOLS, nullptr,
        Hcat + (size_t)OFF(10) * 2048, cbA, nullptr, 2048, 0);

    const float* cprev = cbA;
    float* cbufs[2] = {cbB, cbA};
    int t = 0;
    for (int k = TREE_DEPTH - 2; k >= 0; --k) {
        const int n = 1 << k;
        const u16* A = Hcat + (size_t)OFF(k) * 2048;
        const float* gxk = GX + (size_t)(n - 1) * GCOLS;
        u16* hnext = (k > 0) ? (Hcat + (size_t)OFF(k - 1) * 2048) : nullptr;
        float* cnext = cbufs[t];
        float* outp = (k == 0) ? out : nullptr;

        int KS;
        if (n >= 128) {
            KS = (k == 10) ? 2 : (k == 9) ? 4 : (k == 8) ? 8 : 16;
            dim3 grid(n / 128, GCOLS / 128, KS);
            gemm_big<<<grid, 256, 0, stream>>>(A, 2048, Whh_p, 2048, nullptr,
                                               parts, n, 2048 / KS);
        } else {
            KS = 16;
            dim3 grid((n + 15) / 16, GCOLS / 128, KS);
            gemm_small<<<grid, 256, 0, stream>>>(A, Whh_p, parts, n, 128);
        }
        level_act<<<n, 256, 0, stream>>>(
            parts, KS, (size_t)n * GCOLS, gxk, cprev, hnext, cnext, outp, n, 1);

        cprev = cnext; t ^= 1;
    }
}